// Round 4
// baseline (326.361 us; speedup 1.0000x reference)
//
#include <hip/hip_runtime.h>

#define NCH 64      // channels
#define KOFF 27     // kernel offsets
#define EPSV 1e-5f

typedef __attribute__((ext_vector_type(8))) short  bf16x8;
typedef __attribute__((ext_vector_type(4))) float  f32x4;
typedef __attribute__((ext_vector_type(8))) unsigned short u16x8;

__device__ __forceinline__ unsigned short f2bf(float x) {
    unsigned int u = __float_as_uint(x);
    u += 0x7fffu + ((u >> 16) & 1u);       // round-to-nearest-even
    return (unsigned short)(u >> 16);
}

// ---------------------------------------------------------------------------
// Fused prep: zero stats | W1->Wt1 | W2->Wt2 (B-fragment order) | feats->bf16
// Wt[(((k*2+s)*4+ct)*64+lane)*8 + j] = W[k][s*32+(lane>>4)*8+j][ct*16+(lane&15)]
// ---------------------------------------------------------------------------
__global__ __launch_bounds__(256)
void prep_kernel(const float* __restrict__ feats,
                 const float* __restrict__ W1, const float* __restrict__ W2,
                 unsigned short* __restrict__ fbf,
                 unsigned short* __restrict__ wt1, unsigned short* __restrict__ wt2,
                 float* __restrict__ stat, int total8)
{
    const int b = blockIdx.x;
    if (b == 0) {
        stat[threadIdx.x] = 0.f;           // 256 floats: stats1+stats2
        return;
    }
    if (b <= 108) {
        const float* W = (b <= 54) ? W1 : W2;
        unsigned short* Wt = (b <= 54) ? wt1 : wt2;
        const int t = (b <= 54 ? b - 1 : b - 55) * 256 + threadIdx.x; // 0..13823
        const int l  = t & 63;
        const int ct = (t >> 6) & 3;
        const int s  = (t >> 8) & 1;
        const int k  = t >> 9;
        const int d     = ct * 16 + (l & 15);
        const int cbase = s * 32 + (l >> 4) * 8;
        u16x8 o;
#pragma unroll
        for (int j = 0; j < 8; ++j)
            o[j] = f2bf(W[(size_t)k * 4096 + (size_t)(cbase + j) * 64 + d]);
        reinterpret_cast<u16x8*>(Wt)[t] = o;
        return;
    }
    const int idx = (b - 109) * 256 + threadIdx.x;
    if (idx >= total8) return;
    const float4* xp = reinterpret_cast<const float4*>(feats) + (size_t)idx * 2;
    const float4 a = xp[0], c = xp[1];
    u16x8 o;
    o[0] = f2bf(a.x); o[1] = f2bf(a.y); o[2] = f2bf(a.z); o[3] = f2bf(a.w);
    o[4] = f2bf(c.x); o[5] = f2bf(c.y); o[6] = f2bf(c.z); o[7] = f2bf(c.w);
    reinterpret_cast<u16x8*>(fbf)[idx] = o;
}

// ---------------------------------------------------------------------------
// Gathered conv via MFMA 16x16x32 bf16. 4 waves/block, 128 voxels/block
// (wave wv owns voxels [wv*32, wv*32+32)). WEIGHTS THROUGH LDS: the 27
// 8KB weight tiles are staged in 5 chunks of <=6 offsets (48KB LDS),
// cooperatively by all 256 threads, and read back via conflict-free
// stride-16B ds_read_b128. This amortizes the dominant L1/L2 request
// traffic (B was 675MB/conv re-read per-wave from L2; now 169MB/conv,
// 4x amortized). A-gathers stay register-double-buffered from global.
// Stats: per-WAVE partial rows in pstat (no atomics in the hot kernel).
// ---------------------------------------------------------------------------
__global__ __launch_bounds__(256, 2)
void conv_mfma_kernel(const unsigned short* __restrict__ fin,
                      const int* __restrict__ nbr,
                      const unsigned short* __restrict__ Wt,
                      const float* __restrict__ bias,
                      float* __restrict__ out, float* __restrict__ pstat, int N)
{
    __shared__ int            s_idx[128 * KOFF];   // 13824 B: byte offsets
    __shared__ unsigned short s_w[6 * 4096];       // 49152 B: 6 weight tiles

    const int lane = threadIdx.x & 63;
    const int wv   = threadIdx.x >> 6;        // 0..3
    const int n0   = blockIdx.x * 128;        // block voxel base
    const int m    = lane & 15;
    const int quad = lane >> 4;

    {   // stage 3456 ints cooperatively, pre-scaled to byte offsets
        const int rem  = N - n0;
        const int maxi = (rem < 128 ? rem : 128) * KOFF;
        const int* nb  = nbr + (size_t)n0 * KOFF;
        for (int p = threadIdx.x; p < 128 * KOFF; p += 256)
            s_idx[p] = ((p < maxi) ? nb[p] : 0) * (NCH * 2);
    }

    f32x4 acc[2][4];
#pragma unroll
    for (int mt = 0; mt < 2; ++mt)
#pragma unroll
        for (int ct = 0; ct < 4; ++ct) acc[mt][ct] = (f32x4){0.f, 0.f, 0.f, 0.f};

    bf16x8 A[2][2][2];   // [buf][m-tile][s] : 32 VGPR, double-buffered
    bf16x8 B[2][4];      // [s][ct] from LDS : 32 VGPR
    const char* finB = (const char*)fin;
    const int lv0 = wv * 32;                  // wave's local voxel base

#define LOADA(kk, p)                                                         \
    {                                                                        \
        _Pragma("unroll")                                                    \
        for (int mt = 0; mt < 2; ++mt) {                                     \
            const int ofs = s_idx[(lv0 + mt * 16 + m) * KOFF + (kk)];        \
            const char* fp = finB + ofs + quad * 16;                         \
            A[p][mt][0] = *reinterpret_cast<const bf16x8*>(fp);              \
            A[p][mt][1] = *reinterpret_cast<const bf16x8*>(fp + 64);         \
        }                                                                    \
    }

#define LOADB_LDS(kk)                                                        \
    {                                                                        \
        const unsigned short* wp = s_w + (kk) * 4096 + lane * 8;             \
        _Pragma("unroll")                                                    \
        for (int s = 0; s < 2; ++s)                                          \
            _Pragma("unroll")                                                \
            for (int ct = 0; ct < 4; ++ct)                                   \
                B[s][ct] =                                                   \
                    *reinterpret_cast<const bf16x8*>(wp + (s * 4 + ct) * 512);\
    }

#define DOMFMA(p)                                                            \
    {                                                                        \
        _Pragma("unroll")                                                    \
        for (int mt = 0; mt < 2; ++mt)                                       \
            _Pragma("unroll")                                                \
            for (int s = 0; s < 2; ++s)                                      \
                _Pragma("unroll")                                            \
                for (int ct = 0; ct < 4; ++ct)                               \
                    acc[mt][ct] = __builtin_amdgcn_mfma_f32_16x16x32_bf16(   \
                        A[p][mt][s], B[s][ct], acc[mt][ct], 0, 0, 0);        \
    }

#pragma unroll 1
    for (int c = 0; c < 5; ++c) {
        const int kb  = c * 6;
        const int len = (KOFF - kb < 6) ? (KOFF - kb) : 6;   // 6,6,6,6,3

        // ---- stage weight chunk: len*8KB, coalesced, all 256 threads ----
        {
            const u16x8* gw = reinterpret_cast<const u16x8*>(
                Wt + (size_t)kb * 4096);
            u16x8* lw = reinterpret_cast<u16x8*>(s_w);
            const int units = len * 512;       // 16B units in chunk
#pragma unroll
            for (int i = 0; i < 12; ++i) {     // 12*256 = 3072 >= 6*512
                const int u = threadIdx.x + i * 256;
                if (u < units) lw[u] = gw[u];
            }
        }
        LOADA(kb, 0);                          // first A of chunk in flight
        __syncthreads();                       // s_idx (c==0) + s_w ready

        // ---- compute len k-steps, A double-buffered, B from LDS ----
        int kk = 0;
#pragma unroll 1
        for (; kk + 2 < len; kk += 2) {
            LOADA(kb + kk + 1, 1);
            LOADB_LDS(kk);
            __builtin_amdgcn_sched_barrier(0);
            DOMFMA(0);
            LOADA(kb + kk + 2, 0);
            LOADB_LDS(kk + 1);
            __builtin_amdgcn_sched_barrier(0);
            DOMFMA(1);
        }
        if (kk + 1 < len) {                    // even len: kk, kk+1 remain
            LOADA(kb + kk + 1, 1);
            LOADB_LDS(kk);
            __builtin_amdgcn_sched_barrier(0);
            DOMFMA(0);
            LOADB_LDS(kk + 1);
            __builtin_amdgcn_sched_barrier(0);
            DOMFMA(1);
        } else {                               // odd len: kk remains
            LOADB_LDS(kk);
            __builtin_amdgcn_sched_barrier(0);
            DOMFMA(0);
        }
        __syncthreads();                       // all waves done with s_w
    }
#undef LOADA
#undef LOADB_LDS
#undef DOMFMA

    // epilogue: D layout col=lane&15 (ch), row=quad*4+reg (voxel); per-wave stats
#pragma unroll
    for (int ct = 0; ct < 4; ++ct) {
        const int ch = ct * 16 + m;
        const float bv = bias[ch];
        float s = 0.f, q = 0.f;
#pragma unroll
        for (int mt = 0; mt < 2; ++mt) {
#pragma unroll
            for (int r = 0; r < 4; ++r) {
                const int vox = n0 + lv0 + mt * 16 + quad * 4 + r;
                if (vox < N) {
                    const float v = acc[mt][ct][r] + bv;
                    out[(size_t)vox * NCH + ch] = v;
                    s += v;
                    q += v * v;
                }
            }
        }
        s += __shfl_xor(s, 16, 64);
        s += __shfl_xor(s, 32, 64);
        q += __shfl_xor(q, 16, 64);
        q += __shfl_xor(q, 32, 64);
        if (quad == 0) {
            float* pr = pstat + ((size_t)blockIdx.x * 4 + wv) * 128;
            pr[ch]      = s;
            pr[64 + ch] = q;
        }
    }
}

// ---------------------------------------------------------------------------
// Fold per-wave partial stats into stat[0:128]: coalesced reads, one
// atomicAdd per channel per block (4k lane-atomics total)
// ---------------------------------------------------------------------------
__global__ __launch_bounds__(256)
void reduce_stats_kernel(const float* __restrict__ pstat, float* __restrict__ stat,
                         int rows)
{
    __shared__ float s_[256];
    const int ch = threadIdx.x & 127;
    const int h  = threadIdx.x >> 7;          // 0 or 1
    float acc = 0.f;
    for (int r = blockIdx.x * 2 + h; r < rows; r += gridDim.x * 2)
        acc += pstat[(size_t)r * 128 + ch];
    s_[threadIdx.x] = acc;
    __syncthreads();
    if (threadIdx.x < 128)
        atomicAdd(&stat[threadIdx.x], s_[threadIdx.x] + s_[threadIdx.x + 128]);
}

// ---------------------------------------------------------------------------
// BN + ReLU, fp32 in -> bf16 out (conv2's gather input). 8 elems/thread.
// ---------------------------------------------------------------------------
__global__ __launch_bounds__(256)
void bn_relu_bf16_kernel(const float* __restrict__ x, const float* __restrict__ sums,
                         const float* __restrict__ gmm, const float* __restrict__ bet,
                         float invN, unsigned short* __restrict__ y, int total8)
{
    const int idx = blockIdx.x * 256 + threadIdx.x;
    if (idx >= total8) return;
    const int c0 = (idx & 7) * 8;
    const float4* xp = reinterpret_cast<const float4*>(x) + (size_t)idx * 2;
    const float4 a = xp[0], b = xp[1];
    float v[8] = {a.x, a.y, a.z, a.w, b.x, b.y, b.z, b.w};
    u16x8 o;
#pragma unroll
    for (int i = 0; i < 8; ++i) {
        const int c = c0 + i;
        const float mu  = sums[c] * invN;
        const float var = sums[64 + c] * invN - mu * mu;
        const float rs  = rsqrtf(var + EPSV);
        const float sc  = gmm[c] * rs;
        const float sh  = bet[c] - mu * sc;
        o[i] = f2bf(fmaxf(fmaf(v[i], sc, sh), 0.f));
    }
    reinterpret_cast<u16x8*>(y)[idx] = o;
}

// ---------------------------------------------------------------------------
// BN + residual + ReLU, in-place fp32 (final output)
// ---------------------------------------------------------------------------
__global__ __launch_bounds__(256)
void bn_res_relu_kernel(float* __restrict__ x, const float* __restrict__ feats,
                        const float* __restrict__ sums, const float* __restrict__ gmm,
                        const float* __restrict__ bet, float invN, int total4)
{
    const int idx = blockIdx.x * blockDim.x + threadIdx.x;
    if (idx >= total4) return;
    float4 v = reinterpret_cast<float4*>(x)[idx];
    const float4 f = reinterpret_cast<const float4*>(feats)[idx];
    const int c0 = (idx & 15) * 4;
    float sc[4], sh[4];
#pragma unroll
    for (int i = 0; i < 4; ++i) {
        const int c = c0 + i;
        const float mu  = sums[c] * invN;
        const float var = sums[64 + c] * invN - mu * mu;
        const float rs  = rsqrtf(var + EPSV);
        sc[i] = gmm[c] * rs;
        sh[i] = bet[c] - mu * sc[i];
    }
    v.x = fmaxf(fmaf(v.x, sc[0], sh[0]) + f.x, 0.f);
    v.y = fmaxf(fmaf(v.y, sc[1], sh[1]) + f.y, 0.f);
    v.z = fmaxf(fmaf(v.z, sc[2], sh[2]) + f.z, 0.f);
    v.w = fmaxf(fmaf(v.w, sc[3], sh[3]) + f.w, 0.f);
    reinterpret_cast<float4*>(x)[idx] = v;
}

extern "C" void kernel_launch(void* const* d_in, const int* in_sizes, int n_in,
                              void* d_out, int out_size, void* d_ws, size_t ws_size,
                              hipStream_t stream)
{
    const float* feats = (const float*)d_in[0];
    const int*   nbr   = (const int*)d_in[1];
    const float* W1    = (const float*)d_in[2];
    const float* b1    = (const float*)d_in[3];
    const float* g1    = (const float*)d_in[4];
    const float* be1   = (const float*)d_in[5];
    const float* W2    = (const float*)d_in[6];
    const float* b2    = (const float*)d_in[7];
    const float* g2    = (const float*)d_in[8];
    const float* be2   = (const float*)d_in[9];
    float* out = (float*)d_out;

    const int N  = in_sizes[0] / NCH;          // 100000
    const int NC = N * NCH;                    // 6,400,000
    const float invN = 1.0f / (float)N;

    // workspace layout
    float*          h0   = (float*)d_ws;                       // [N*C] fp32
    unsigned short* fbf  = (unsigned short*)(h0 + NC);         // [N*C] bf16
    unsigned short* hbf  = fbf + NC;                           // [N*C] bf16
    unsigned short* wt1  = hbf + NC;                           // 110592 bf16
    unsigned short* wt2  = wt1 + KOFF * 4096;                  // 110592 bf16
    float*          stat = (float*)(wt2 + KOFF * 4096);        // 256 fp32

    const int total8   = NC / 8;                               // 800000
    const int castGrid = (total8 + 255) / 256;                 // 3125
    const int prepGrid = 1 + 108 + castGrid;                   // 3234
    const int convGrid = (N + 127) / 128;                      // 782
    const int statRows = convGrid * 4;                         // per-wave rows

    // pstat scratch aliases dead regions: conv1's partials go in d_out
    // (overwritten later by conv2), conv2's partials go in h0 (dead after bn).
    float* pstat1 = out;
    float* pstat2 = h0;

    prep_kernel<<<prepGrid, 256, 0, stream>>>(feats, W1, W2, fbf, wt1, wt2,
                                              stat, total8);
    conv_mfma_kernel<<<convGrid, 256, 0, stream>>>(fbf, nbr, wt1, b1, h0,
                                                   pstat1, N);
    reduce_stats_kernel<<<32, 256, 0, stream>>>(pstat1, stat, statRows);
    bn_relu_bf16_kernel<<<castGrid, 256, 0, stream>>>(h0, stat, g1, be1, invN,
                                                      hbf, total8);
    conv_mfma_kernel<<<convGrid, 256, 0, stream>>>(hbf, nbr, wt2, b2, out,
                                                   pstat2, N);
    reduce_stats_kernel<<<32, 256, 0, stream>>>(pstat2, stat + 128, statRows);
    bn_res_relu_kernel<<<(NC / 4 + 255) / 256, 256, 0, stream>>>(
        out, feats, stat + 128, g2, be2, invN, NC / 4);
}

// Round 5
// 286.253 us; speedup vs baseline: 1.1401x; 1.1401x over previous
//
#include <hip/hip_runtime.h>

#define NCH 64      // channels
#define KOFF 27     // kernel offsets
#define EPSV 1e-5f

typedef __attribute__((ext_vector_type(8))) short  bf16x8;
typedef __attribute__((ext_vector_type(4))) float  f32x4;
typedef __attribute__((ext_vector_type(8))) unsigned short u16x8;

__device__ __forceinline__ unsigned short f2bf(float x) {
    unsigned int u = __float_as_uint(x);
    u += 0x7fffu + ((u >> 16) & 1u);       // round-to-nearest-even
    return (unsigned short)(u >> 16);
}

// ---------------------------------------------------------------------------
// Fused prep: zero stats | W1->Wt1 | W2->Wt2 (B-fragment order) | feats->bf16
// Wt[(((k*2+s)*4+ct)*64+lane)*8 + j] = W[k][s*32+(lane>>4)*8+j][ct*16+(lane&15)]
// ---------------------------------------------------------------------------
__global__ __launch_bounds__(256)
void prep_kernel(const float* __restrict__ feats,
                 const float* __restrict__ W1, const float* __restrict__ W2,
                 unsigned short* __restrict__ fbf,
                 unsigned short* __restrict__ wt1, unsigned short* __restrict__ wt2,
                 float* __restrict__ stat, int total8)
{
    const int b = blockIdx.x;
    if (b == 0) {
        stat[threadIdx.x] = 0.f;           // 256 floats: stats1+stats2
        return;
    }
    if (b <= 108) {
        const float* W = (b <= 54) ? W1 : W2;
        unsigned short* Wt = (b <= 54) ? wt1 : wt2;
        const int t = (b <= 54 ? b - 1 : b - 55) * 256 + threadIdx.x; // 0..13823
        const int l  = t & 63;
        const int ct = (t >> 6) & 3;
        const int s  = (t >> 8) & 1;
        const int k  = t >> 9;
        const int d     = ct * 16 + (l & 15);
        const int cbase = s * 32 + (l >> 4) * 8;
        u16x8 o;
#pragma unroll
        for (int j = 0; j < 8; ++j)
            o[j] = f2bf(W[(size_t)k * 4096 + (size_t)(cbase + j) * 64 + d]);
        reinterpret_cast<u16x8*>(Wt)[t] = o;
        return;
    }
    const int idx = (b - 109) * 256 + threadIdx.x;
    if (idx >= total8) return;
    const float4* xp = reinterpret_cast<const float4*>(feats) + (size_t)idx * 2;
    const float4 a = xp[0], c = xp[1];
    u16x8 o;
    o[0] = f2bf(a.x); o[1] = f2bf(a.y); o[2] = f2bf(a.z); o[3] = f2bf(a.w);
    o[4] = f2bf(c.x); o[5] = f2bf(c.y); o[6] = f2bf(c.z); o[7] = f2bf(c.w);
    reinterpret_cast<u16x8*>(fbf)[idx] = o;
}

// ---------------------------------------------------------------------------
// Gathered conv via MFMA 16x16x32 bf16. 4 waves/block, 128 voxels/block.
// Weights through LDS in 9 chunks of 3 offsets (24KB) so total LDS = 38.4KB
// -> 4 blocks/CU capacity; grid is 782 blocks = 3.05/CU, so ALL blocks are
// resident for the whole kernel (~12 waves/CU, no tail). B reads are
// conflict-free stride-16B ds_read_b128; A-gathers register-double-buffered
// from global with compile-time parity A[k&1] (c-loop fully unrolled).
// Stats: per-wave partial rows in pstat, no atomics here.
// ---------------------------------------------------------------------------
__global__ __launch_bounds__(256, 4)
void conv_mfma_kernel(const unsigned short* __restrict__ fin,
                      const int* __restrict__ nbr,
                      const unsigned short* __restrict__ Wt,
                      const float* __restrict__ bias,
                      float* __restrict__ out, float* __restrict__ pstat, int N)
{
    __shared__ int            s_idx[128 * KOFF];   // 13824 B: byte offsets
    __shared__ unsigned short s_w[3 * 4096];       // 24576 B: 3 weight tiles

    const int lane = threadIdx.x & 63;
    const int wv   = threadIdx.x >> 6;        // 0..3
    const int n0   = blockIdx.x * 128;        // block voxel base
    const int m    = lane & 15;
    const int quad = lane >> 4;

    {   // stage 3456 ints cooperatively, pre-scaled to byte offsets
        const int rem  = N - n0;
        const int maxi = (rem < 128 ? rem : 128) * KOFF;
        const int* nb  = nbr + (size_t)n0 * KOFF;
        for (int p = threadIdx.x; p < 128 * KOFF; p += 256)
            s_idx[p] = ((p < maxi) ? nb[p] : 0) * (NCH * 2);
    }
    __syncthreads();                           // s_idx ready (fixes r4 race)

    f32x4 acc[2][4];
#pragma unroll
    for (int mt = 0; mt < 2; ++mt)
#pragma unroll
        for (int ct = 0; ct < 4; ++ct) acc[mt][ct] = (f32x4){0.f, 0.f, 0.f, 0.f};

    bf16x8 A[2][2][2];   // [k&1][m-tile][s] : 32 VGPR, double-buffered
    bf16x8 B[2][4];      // [s][ct] from LDS : 32 VGPR
    const char* finB = (const char*)fin;
    const int lv0 = wv * 32;                  // wave's local voxel base

#define LOADA(kk)                                                            \
    {                                                                        \
        _Pragma("unroll")                                                    \
        for (int mt = 0; mt < 2; ++mt) {                                     \
            const int ofs = s_idx[(lv0 + mt * 16 + m) * KOFF + (kk)];        \
            const char* fp = finB + ofs + quad * 16;                         \
            A[(kk) & 1][mt][0] = *reinterpret_cast<const bf16x8*>(fp);       \
            A[(kk) & 1][mt][1] = *reinterpret_cast<const bf16x8*>(fp + 64);  \
        }                                                                    \
    }

#define LOADB_LDS(kk)                                                        \
    {                                                                        \
        const unsigned short* wp = s_w + (kk) * 4096 + lane * 8;             \
        _Pragma("unroll")                                                    \
        for (int s = 0; s < 2; ++s)                                          \
            _Pragma("unroll")                                                \
            for (int ct = 0; ct < 4; ++ct)                                   \
                B[s][ct] =                                                   \
                    *reinterpret_cast<const bf16x8*>(wp + (s * 4 + ct) * 512);\
    }

#define DOMFMA(kk)                                                           \
    {                                                                        \
        _Pragma("unroll")                                                    \
        for (int mt = 0; mt < 2; ++mt)                                       \
            _Pragma("unroll")                                                \
            for (int s = 0; s < 2; ++s)                                      \
                _Pragma("unroll")                                            \
                for (int ct = 0; ct < 4; ++ct)                               \
                    acc[mt][ct] = __builtin_amdgcn_mfma_f32_16x16x32_bf16(   \
                        A[(kk) & 1][mt][s], B[s][ct], acc[mt][ct], 0, 0, 0); \
    }

    LOADA(0);                                  // first A prefetch in flight

#pragma unroll
    for (int c = 0; c < 9; ++c) {
        const int kb = c * 3;                  // compile-time (full unroll)

        // ---- stage weight chunk: 3*8KB, coalesced, all 256 threads ----
        {
            const u16x8* gw = reinterpret_cast<const u16x8*>(
                Wt + (size_t)kb * 4096);
            u16x8* lw = reinterpret_cast<u16x8*>(s_w);
#pragma unroll
            for (int i = 0; i < 6; ++i)        // 6*256 = 1536 = 3*512 units
                lw[threadIdx.x + i * 256] = gw[threadIdx.x + i * 256];
        }
        __syncthreads();                       // s_w ready

        // ---- 3 k-steps, A double-buffered by global parity, B from LDS ----
        LOADA(kb + 1);
        LOADB_LDS(0);
        __builtin_amdgcn_sched_barrier(0);
        DOMFMA(kb);

        LOADA(kb + 2);
        LOADB_LDS(1);
        __builtin_amdgcn_sched_barrier(0);
        DOMFMA(kb + 1);

        if (c < 8) LOADA(kb + 3);              // prefetch next chunk's first A
        LOADB_LDS(2);
        __builtin_amdgcn_sched_barrier(0);
        DOMFMA(kb + 2);

        __syncthreads();                       // all waves done with s_w
    }
#undef LOADA
#undef LOADB_LDS
#undef DOMFMA

    // epilogue: D layout col=lane&15 (ch), row=quad*4+reg (voxel); per-wave stats
#pragma unroll
    for (int ct = 0; ct < 4; ++ct) {
        const int ch = ct * 16 + m;
        const float bv = bias[ch];
        float s = 0.f, q = 0.f;
#pragma unroll
        for (int mt = 0; mt < 2; ++mt) {
#pragma unroll
            for (int r = 0; r < 4; ++r) {
                const int vox = n0 + lv0 + mt * 16 + quad * 4 + r;
                if (vox < N) {
                    const float v = acc[mt][ct][r] + bv;
                    out[(size_t)vox * NCH + ch] = v;
                    s += v;
                    q += v * v;
                }
            }
        }
        s += __shfl_xor(s, 16, 64);
        s += __shfl_xor(s, 32, 64);
        q += __shfl_xor(q, 16, 64);
        q += __shfl_xor(q, 32, 64);
        if (quad == 0) {
            float* pr = pstat + ((size_t)blockIdx.x * 4 + wv) * 128;
            pr[ch]      = s;
            pr[64 + ch] = q;
        }
    }
}

// ---------------------------------------------------------------------------
// Fold per-wave partial stats into stat[0:128]: coalesced reads, one
// atomicAdd per channel per block (4k lane-atomics total)
// ---------------------------------------------------------------------------
__global__ __launch_bounds__(256)
void reduce_stats_kernel(const float* __restrict__ pstat, float* __restrict__ stat,
                         int rows)
{
    __shared__ float s_[256];
    const int ch = threadIdx.x & 127;
    const int h  = threadIdx.x >> 7;          // 0 or 1
    float acc = 0.f;
    for (int r = blockIdx.x * 2 + h; r < rows; r += gridDim.x * 2)
        acc += pstat[(size_t)r * 128 + ch];
    s_[threadIdx.x] = acc;
    __syncthreads();
    if (threadIdx.x < 128)
        atomicAdd(&stat[threadIdx.x], s_[threadIdx.x] + s_[threadIdx.x + 128]);
}

// ---------------------------------------------------------------------------
// BN + ReLU, fp32 in -> bf16 out (conv2's gather input). 8 elems/thread.
// ---------------------------------------------------------------------------
__global__ __launch_bounds__(256)
void bn_relu_bf16_kernel(const float* __restrict__ x, const float* __restrict__ sums,
                         const float* __restrict__ gmm, const float* __restrict__ bet,
                         float invN, unsigned short* __restrict__ y, int total8)
{
    const int idx = blockIdx.x * 256 + threadIdx.x;
    if (idx >= total8) return;
    const int c0 = (idx & 7) * 8;
    const float4* xp = reinterpret_cast<const float4*>(x) + (size_t)idx * 2;
    const float4 a = xp[0], b = xp[1];
    float v[8] = {a.x, a.y, a.z, a.w, b.x, b.y, b.z, b.w};
    u16x8 o;
#pragma unroll
    for (int i = 0; i < 8; ++i) {
        const int c = c0 + i;
        const float mu  = sums[c] * invN;
        const float var = sums[64 + c] * invN - mu * mu;
        const float rs  = rsqrtf(var + EPSV);
        const float sc  = gmm[c] * rs;
        const float sh  = bet[c] - mu * sc;
        o[i] = f2bf(fmaxf(fmaf(v[i], sc, sh), 0.f));
    }
    reinterpret_cast<u16x8*>(y)[idx] = o;
}

// ---------------------------------------------------------------------------
// BN + residual + ReLU, in-place fp32 (final output)
// ---------------------------------------------------------------------------
__global__ __launch_bounds__(256)
void bn_res_relu_kernel(float* __restrict__ x, const float* __restrict__ feats,
                        const float* __restrict__ sums, const float* __restrict__ gmm,
                        const float* __restrict__ bet, float invN, int total4)
{
    const int idx = blockIdx.x * blockDim.x + threadIdx.x;
    if (idx >= total4) return;
    float4 v = reinterpret_cast<float4*>(x)[idx];
    const float4 f = reinterpret_cast<const float4*>(feats)[idx];
    const int c0 = (idx & 15) * 4;
    float sc[4], sh[4];
#pragma unroll
    for (int i = 0; i < 4; ++i) {
        const int c = c0 + i;
        const float mu  = sums[c] * invN;
        const float var = sums[64 + c] * invN - mu * mu;
        const float rs  = rsqrtf(var + EPSV);
        sc[i] = gmm[c] * rs;
        sh[i] = bet[c] - mu * sc[i];
    }
    v.x = fmaxf(fmaf(v.x, sc[0], sh[0]) + f.x, 0.f);
    v.y = fmaxf(fmaf(v.y, sc[1], sh[1]) + f.y, 0.f);
    v.z = fmaxf(fmaf(v.z, sc[2], sh[2]) + f.z, 0.f);
    v.w = fmaxf(fmaf(v.w, sc[3], sh[3]) + f.w, 0.f);
    reinterpret_cast<float4*>(x)[idx] = v;
}

extern "C" void kernel_launch(void* const* d_in, const int* in_sizes, int n_in,
                              void* d_out, int out_size, void* d_ws, size_t ws_size,
                              hipStream_t stream)
{
    const float* feats = (const float*)d_in[0];
    const int*   nbr   = (const int*)d_in[1];
    const float* W1    = (const float*)d_in[2];
    const float* b1    = (const float*)d_in[3];
    const float* g1    = (const float*)d_in[4];
    const float* be1   = (const float*)d_in[5];
    const float* W2    = (const float*)d_in[6];
    const float* b2    = (const float*)d_in[7];
    const float* g2    = (const float*)d_in[8];
    const float* be2   = (const float*)d_in[9];
    float* out = (float*)d_out;

    const int N  = in_sizes[0] / NCH;          // 100000
    const int NC = N * NCH;                    // 6,400,000
    const float invN = 1.0f / (float)N;

    // workspace layout
    float*          h0   = (float*)d_ws;                       // [N*C] fp32
    unsigned short* fbf  = (unsigned short*)(h0 + NC);         // [N*C] bf16
    unsigned short* hbf  = fbf + NC;                           // [N*C] bf16
    unsigned short* wt1  = hbf + NC;                           // 110592 bf16
    unsigned short* wt2  = wt1 + KOFF * 4096;                  // 110592 bf16
    float*          stat = (float*)(wt2 + KOFF * 4096);        // 256 fp32

    const int total8   = NC / 8;                               // 800000
    const int castGrid = (total8 + 255) / 256;                 // 3125
    const int prepGrid = 1 + 108 + castGrid;                   // 3234
    const int convGrid = (N + 127) / 128;                      // 782
    const int statRows = convGrid * 4;                         // per-wave rows

    // pstat scratch aliases dead regions: conv1's partials go in d_out
    // (overwritten later by conv2), conv2's partials go in h0 (dead after bn).
    float* pstat1 = out;
    float* pstat2 = h0;

    prep_kernel<<<prepGrid, 256, 0, stream>>>(feats, W1, W2, fbf, wt1, wt2,
                                              stat, total8);
    conv_mfma_kernel<<<convGrid, 256, 0, stream>>>(fbf, nbr, wt1, b1, h0,
                                                   pstat1, N);
    reduce_stats_kernel<<<32, 256, 0, stream>>>(pstat1, stat, statRows);
    bn_relu_bf16_kernel<<<castGrid, 256, 0, stream>>>(h0, stat, g1, be1, invN,
                                                      hbf, total8);
    conv_mfma_kernel<<<convGrid, 256, 0, stream>>>(hbf, nbr, wt2, b2, out,
                                                   pstat2, N);
    reduce_stats_kernel<<<32, 256, 0, stream>>>(pstat2, stat + 128, statRows);
    bn_res_relu_kernel<<<(NC / 4 + 255) / 256, 256, 0, stream>>>(
        out, feats, stat + 128, g2, be2, invN, NC / 4);
}